// Round 5
// baseline (197.949 us; speedup 1.0000x reference)
//
#include <hip/hip_runtime.h>

#define N_NODES 50000
#define N_EDGES 600000
#define CH 128
#define NUM_GRAPHS 512
#define OUT_CH 64
// padded bucket stride (max degree safety: Poisson(12), P(>=64) ~ 0)
#define DSH 6
#define DSTRIDE 64
// cur padding: one 64B cache line per node counter
#define CURSH 4
// partitioned fill: 8 dst-range groups (one per XCD), 1 edge/thread for max MLP
#define PF_GROUPS 8
#define PF_SLICE (N_NODES / PF_GROUPS)           // 6250
#define PF_CHUNKS ((N_EDGES + 255) / 256)        // 2344

typedef unsigned int uint32;
typedef __attribute__((ext_vector_type(8))) short short8;
typedef __attribute__((ext_vector_type(4))) float floatx4;

// pack two fp32 -> bf16x2 (RNE), lo = first channel
__device__ __forceinline__ uint32 bfpack(float a, float b) {
    uint32 ua = __builtin_bit_cast(uint32, a);
    uint32 ub = __builtin_bit_cast(uint32, b);
    ua = (ua + 0x7fffu + ((ua >> 16) & 1u)) >> 16;
    ub = (ub + 0x7fffu + ((ub >> 16) & 1u)) >> 16;
    return (ub << 16) | ua;
}
__device__ __forceinline__ unsigned short bfr(float f) {
    uint32 u = __builtin_bit_cast(uint32, f);
    u = (u + 0x7fffu + ((u >> 16) & 1u)) >> 16;
    return (unsigned short)u;
}
__device__ __forceinline__ float bf_lo(uint32 v) {
    return __builtin_bit_cast(float, v << 16);
}
__device__ __forceinline__ float bf_hi(uint32 v) {
    return __builtin_bit_cast(float, v & 0xffff0000u);
}

// ---------------- prep: zero cur (padded, 3.2MB) + W1,W2 -> bf16 transposed ----------
__global__ void k_prep(const float* __restrict__ W1, const float* __restrict__ W2,
                       unsigned short* __restrict__ W1t, unsigned short* __restrict__ W2t,
                       int* __restrict__ cur) {
    int idx = blockIdx.x * 256 + threadIdx.x;
    int4* cur4 = (int4*)cur;
    int4 z = make_int4(0, 0, 0, 0);
    #pragma unroll
    for (int k = 0; k < 4; ++k) {
        int i = idx + k * 50176;
        if (i < 200000) cur4[i] = z;
    }
    if (idx < 32768) {
        int mat = idx >> 14;
        int rem = idx & 16383;
        int k = rem >> 7, c = rem & 127;
        const float* W = mat ? W2 : W1;
        unsigned short* Wt = mat ? W2t : W1t;
        Wt[c * 128 + k] = bfr(W[k * 128 + c]);
    }
}

// ---------------- partitioned padded-CSR build, 1 edge/thread ----------------
// fill wall ~40us is insensitive to occupancy (r3), partitioning (r2), and cur
// line-padding (r4) -> memory-side returning-atomic throughput. Left as-is this
// round; next lever is overlap or atomic-count reduction, not locality.
__global__ __launch_bounds__(256) void k_fill_part(const int* __restrict__ src,
                                                   const int* __restrict__ dst,
                                                   int* __restrict__ cur,
                                                   int* __restrict__ srcs) {
    int g = blockIdx.x & (PF_GROUPS - 1);
    int chunk = blockIdx.x >> 3;
    int e = chunk * 256 + threadIdx.x;
    if (e < N_EDGES) {
        int d = dst[e];
        if ((unsigned)(d - g * PF_SLICE) < (unsigned)PF_SLICE) {
            int s = src[e];
            int p = atomicAdd(&cur[d << CURSH], 1);
            srcs[(d << DSH) + p] = s;
        }
    }
}

// ---------------- MFMA GEMM: outb[N,128](bf16) = bf16(dinv * (A @ W)) ----------------
// A: fp32 [N][128] (AF32=true, packs to bf16 during staging) or bf16 [N][128].
// Wt: bf16 transposed [col][k]. 256 thr = 4 waves, block tile 128x128;
// wave = 2 row-tiles x 8 col-tiles of 16x16x32 MFMA.
template <bool AF32>
__global__ __launch_bounds__(256, 2) void k_gemm(const void* __restrict__ Av,
                                                 const unsigned short* __restrict__ Wt,
                                                 const int* __restrict__ cur,
                                                 unsigned short* __restrict__ outb) {
    __shared__ __align__(16) unsigned short as_[128][136];  // +8 pad: stride 272B
    __shared__ __align__(16) unsigned short bs[128][136];
    int tid = threadIdx.x;
    int row0 = blockIdx.x * 128;

    #pragma unroll
    for (int it = 0; it < 8; ++it) {            // A tile: 128 rows x 16 segs x 8 ch
        int idx = it * 256 + tid;
        int r = idx >> 4, seg = idx & 15;
        int gr = min(row0 + r, N_NODES - 1);
        if (AF32) {
            const float4* ap = (const float4*)((const float*)Av + (size_t)gr * 128 + seg * 8);
            float4 v0 = ap[0], v1 = ap[1];
            uint4 pk;
            pk.x = bfpack(v0.x, v0.y); pk.y = bfpack(v0.z, v0.w);
            pk.z = bfpack(v1.x, v1.y); pk.w = bfpack(v1.z, v1.w);
            *(uint4*)&as_[r][seg * 8] = pk;
        } else {
            *(uint4*)&as_[r][seg * 8] =
                *(const uint4*)((const unsigned short*)Av + (size_t)gr * 128 + seg * 8);
        }
    }
    #pragma unroll
    for (int it = 0; it < 8; ++it) {            // Wt tile: 128 cols x 256B
        int idx = it * 256 + tid;
        int c = idx >> 4, seg = idx & 15;
        *(uint4*)&bs[c][seg * 8] = *(const uint4*)&Wt[c * 128 + seg * 8];
    }
    __syncthreads();

    int w = tid >> 6, lane = tid & 63, q = lane >> 4, m = lane & 15;
    int q8 = q * 8;
    floatx4 acc[2][8];
    #pragma unroll
    for (int rt = 0; rt < 2; ++rt)
        #pragma unroll
        for (int ct = 0; ct < 8; ++ct) {
            floatx4 z = {0.f, 0.f, 0.f, 0.f};
            acc[rt][ct] = z;
        }

    #pragma unroll
    for (int kc = 0; kc < 128; kc += 32) {
        short8 a0 = *(const short8*)&as_[w * 32 + m][kc + q8];
        short8 a1 = *(const short8*)&as_[w * 32 + 16 + m][kc + q8];
        #pragma unroll
        for (int ct = 0; ct < 8; ++ct) {
            short8 b = *(const short8*)&bs[ct * 16 + m][kc + q8];
            acc[0][ct] = __builtin_amdgcn_mfma_f32_16x16x32_bf16(a0, b, acc[0][ct], 0, 0, 0);
            acc[1][ct] = __builtin_amdgcn_mfma_f32_16x16x32_bf16(a1, b, acc[1][ct], 0, 0, 0);
        }
    }

    #pragma unroll
    for (int rt = 0; rt < 2; ++rt) {
        #pragma unroll
        for (int i = 0; i < 4; ++i) {
            int gr = row0 + w * 32 + rt * 16 + q * 4 + i;
            if (gr < N_NODES) {
                float sc = rsqrtf((float)(cur[gr << CURSH] + 1));
                #pragma unroll
                for (int ct = 0; ct < 8; ++ct) {
                    outb[(size_t)gr * 128 + ct * 16 + m] = bfr(acc[rt][ct][i] * sc);
                }
            }
        }
    }
}

// ---------------- aggregation: padded buckets, VECTORIZED 16B/lane gathers ----------
// wave = 1 node; 4 groups x 16 lanes; group fetches one full 256B src row per
// instruction (16 lanes x uint4); one wave-instruction gathers 4 rows = 1KB.
// Was 64x4B/row (request-rate bound ~4TB/s by Little's law); now 16x16B/row.
// Cross-group partials combined via __shfl_xor(16/32). 2 rounds unrolled
// (8 rows in flight = same bytes in flight as old code, 1/4 the requests).
// BF16OUT: bf16 (layer1 -> gemm2 input); else fp32 (layer2 -> pool).
template <bool BF16OUT>
__global__ __launch_bounds__(256) void k_agg(const uint32* __restrict__ hb,
                                             const int* __restrict__ cnt_arr,
                                             const int* __restrict__ srcs,
                                             const float* __restrict__ bias,
                                             void* __restrict__ outv) {
    int node = __builtin_amdgcn_readfirstlane(blockIdx.x * 4 + (threadIdx.x >> 6));
    int lane = threadIdx.x & 63;
    int grp = lane >> 4;        // which src of a 4-edge round
    int seg = lane & 15;        // 16B segment of the 256B row (channels seg*8..seg*8+7)

    int cnt = cnt_arr[node << CURSH];
    float dn = rsqrtf((float)(cnt + 1));
    const uint4* hb4 = (const uint4*)hb;     // row = 16 uint4

    float ax0 = 0.f, ay0 = 0.f, ax1 = 0.f, ay1 = 0.f;
    float ax2 = 0.f, ay2 = 0.f, ax3 = 0.f, ay3 = 0.f;

    int start = node << DSH;
    int cl = cnt - 1;
    for (int j = 0; j < cnt; j += 8) {
        int pa = j + grp;
        int pb = pa + 4;
        int sa = srcs[start + min(pa, cl)];
        int sb = srcs[start + min(pb, cl)];
        uint4 va = hb4[(size_t)sa * 16 + seg];
        uint4 vb = hb4[(size_t)sb * 16 + seg];
        if (pa >= cnt) { va.x = 0u; va.y = 0u; va.z = 0u; va.w = 0u; }
        if (pb >= cnt) { vb.x = 0u; vb.y = 0u; vb.z = 0u; vb.w = 0u; }
        ax0 += bf_lo(va.x); ay0 += bf_hi(va.x);
        ax1 += bf_lo(va.y); ay1 += bf_hi(va.y);
        ax2 += bf_lo(va.z); ay2 += bf_hi(va.z);
        ax3 += bf_lo(va.w); ay3 += bf_hi(va.w);
        ax0 += bf_lo(vb.x); ay0 += bf_hi(vb.x);
        ax1 += bf_lo(vb.y); ay1 += bf_hi(vb.y);
        ax2 += bf_lo(vb.z); ay2 += bf_hi(vb.z);
        ax3 += bf_lo(vb.w); ay3 += bf_hi(vb.w);
    }

    // combine the 4 group partials (lanes differing in bits 4-5)
    ax0 += __shfl_xor(ax0, 16, 64); ax0 += __shfl_xor(ax0, 32, 64);
    ay0 += __shfl_xor(ay0, 16, 64); ay0 += __shfl_xor(ay0, 32, 64);
    ax1 += __shfl_xor(ax1, 16, 64); ax1 += __shfl_xor(ax1, 32, 64);
    ay1 += __shfl_xor(ay1, 16, 64); ay1 += __shfl_xor(ay1, 32, 64);
    ax2 += __shfl_xor(ax2, 16, 64); ax2 += __shfl_xor(ax2, 32, 64);
    ay2 += __shfl_xor(ay2, 16, 64); ay2 += __shfl_xor(ay2, 32, 64);
    ax3 += __shfl_xor(ax3, 16, 64); ax3 += __shfl_xor(ax3, 32, 64);
    ay3 += __shfl_xor(ay3, 16, 64); ay3 += __shfl_xor(ay3, 32, 64);

    // self-loop row (bf16(dinv[n]*h[n])), bias, relu
    uint4 vs = hb4[(size_t)node * 16 + seg];
    ax0 += bf_lo(vs.x); ay0 += bf_hi(vs.x);
    ax1 += bf_lo(vs.y); ay1 += bf_hi(vs.y);
    ax2 += bf_lo(vs.z); ay2 += bf_hi(vs.z);
    ax3 += bf_lo(vs.w); ay3 += bf_hi(vs.w);

    float4 b0 = *(const float4*)&bias[seg * 8];
    float4 b1 = *(const float4*)&bias[seg * 8 + 4];
    float r0 = fmaxf(ax0 * dn + b0.x, 0.f);
    float r1 = fmaxf(ay0 * dn + b0.y, 0.f);
    float r2 = fmaxf(ax1 * dn + b0.z, 0.f);
    float r3 = fmaxf(ay1 * dn + b0.w, 0.f);
    float r4 = fmaxf(ax2 * dn + b1.x, 0.f);
    float r5 = fmaxf(ay2 * dn + b1.y, 0.f);
    float r6 = fmaxf(ax3 * dn + b1.z, 0.f);
    float r7 = fmaxf(ay3 * dn + b1.w, 0.f);

    if (grp == 0) {
        if (BF16OUT) {
            uint4 pk;
            pk.x = bfpack(r0, r1); pk.y = bfpack(r2, r3);
            pk.z = bfpack(r4, r5); pk.w = bfpack(r6, r7);
            ((uint4*)outv)[(size_t)node * 16 + seg] = pk;
        } else {
            float4 o0 = make_float4(r0, r1, r2, r3);
            float4 o1 = make_float4(r4, r5, r6, r7);
            ((float4*)outv)[(size_t)node * 32 + seg * 2] = o0;
            ((float4*)outv)[(size_t)node * 32 + seg * 2 + 1] = o1;
        }
    }
}

// ---------------- fused mean-pool + linear (batch is sorted) ----------------
__global__ __launch_bounds__(256) void k_pool_linear(const float* __restrict__ h,
                                                     const int* __restrict__ batch,
                                                     const float* __restrict__ Wl,
                                                     const float* __restrict__ bl,
                                                     float* __restrict__ out) {
    __shared__ int sb[2];
    __shared__ float4 sacc[256];
    __shared__ float xr[CH];
    __shared__ float po[4][OUT_CH];
    int g = blockIdx.x;
    int tid = threadIdx.x;
    if (tid < 2) {
        int target = g + tid;
        int lo = 0, hi = N_NODES;
        while (lo < hi) {
            int mid = (lo + hi) >> 1;
            if (batch[mid] < target) lo = mid + 1; else hi = mid;
        }
        sb[tid] = lo;
    }
    __syncthreads();
    int lo = sb[0], hi = sb[1];
    int q = tid & 31;   // channel quad
    int r = tid >> 5;   // row phase 0..7
    const float4* h4 = (const float4*)h;
    float4 acc = make_float4(0.f, 0.f, 0.f, 0.f);
    for (int i = lo + r; i < hi; i += 8) {
        float4 v = h4[(size_t)i * 32 + q];
        acc.x += v.x; acc.y += v.y; acc.z += v.z; acc.w += v.w;
    }
    sacc[tid] = acc;
    __syncthreads();
    if (r == 0) {
        #pragma unroll
        for (int p = 1; p < 8; ++p) {
            float4 t = sacc[q + p * 32];
            acc.x += t.x; acc.y += t.y; acc.z += t.z; acc.w += t.w;
        }
        float inv = 1.f / (float)((hi - lo) > 0 ? (hi - lo) : 1);
        xr[q * 4 + 0] = acc.x * inv;
        xr[q * 4 + 1] = acc.y * inv;
        xr[q * 4 + 2] = acc.z * inv;
        xr[q * 4 + 3] = acc.w * inv;
    }
    __syncthreads();
    int c = tid & 63;
    int kh = tid >> 6;
    float o = 0.f;
    #pragma unroll 8
    for (int k = kh * 32; k < kh * 32 + 32; ++k) o += xr[k] * Wl[k * OUT_CH + c];
    po[kh][c] = o;
    __syncthreads();
    if (tid < OUT_CH) {
        float v = bl[tid] + po[0][tid] + po[1][tid] + po[2][tid] + po[3][tid];
        out[g * OUT_CH + tid] = v;
    }
}

extern "C" void kernel_launch(void* const* d_in, const int* in_sizes, int n_in,
                              void* d_out, int out_size, void* d_ws, size_t ws_size,
                              hipStream_t stream) {
    const float* x    = (const float*)d_in[0];
    const float* W1   = (const float*)d_in[1];
    const float* b1   = (const float*)d_in[2];
    const float* W2   = (const float*)d_in[3];
    const float* b2   = (const float*)d_in[4];
    const float* Wlin = (const float*)d_in[5];
    const float* blin = (const float*)d_in[6];
    const int* ei     = (const int*)d_in[7];
    const int* batch  = (const int*)d_in[8];
    const int* esrc = ei;
    const int* edst = ei + N_EDGES;
    float* out = (float*)d_out;

    char* w = (char*)d_ws;
    size_t o = 0;
    float* hA            = (float*)(w + o);          o += (size_t)N_NODES * CH * 4;      // fp32 agg2 out
    unsigned short* hb   = (unsigned short*)(w + o); o += (size_t)N_NODES * CH * 2;      // bf16 prescaled gemm out
    uint32* habf         = (uint32*)(w + o);         o += (size_t)N_NODES * 64 * 4;      // bf16 agg1 out
    unsigned short* W1t  = (unsigned short*)(w + o); o += 16384 * 2;
    unsigned short* W2t  = (unsigned short*)(w + o); o += 16384 * 2;
    int* srcs            = (int*)(w + o);            o += (size_t)N_NODES * DSTRIDE * 4; // padded buckets
    int* cur             = (int*)(w + o);            o += (size_t)N_NODES * 64;          // 1 line/node
    (void)ws_size; (void)in_sizes; (void)n_in; (void)out_size;

    dim3 b256(256);
    k_prep<<<dim3(196), b256, 0, stream>>>(W1, W2, W1t, W2t, cur);
    k_fill_part<<<dim3(PF_GROUPS * PF_CHUNKS), b256, 0, stream>>>(esrc, edst, cur, srcs);

    dim3 gG((N_NODES + 127) / 128);   // 391 blocks
    dim3 gA(N_NODES / 4);             // 12500 blocks, one wave64 per node
    k_gemm<true><<<gG, b256, 0, stream>>>(x, W1t, cur, hb);
    k_agg<true><<<gA, b256, 0, stream>>>((const uint32*)hb, cur, srcs, b1, habf);
    k_gemm<false><<<gG, b256, 0, stream>>>(habf, W2t, cur, hb);
    k_agg<false><<<gA, b256, 0, stream>>>((const uint32*)hb, cur, srcs, b2, hA);
    k_pool_linear<<<dim3(NUM_GRAPHS), b256, 0, stream>>>(hA, batch, Wlin, blin, out);
}